// Round 9
// baseline (188.047 us; speedup 1.0000x reference)
//
#include <hip/hip_runtime.h>

// Geometry: M=N=128, padded S=256. Two volumes (b*d=2).
// A: [v][z<128][y:256][x:256] complex FP16-PACKED (uint32 = re:f16 | im:f16<<16) = 67 MB.
// B (packed): [v][z<128][y:256][x<128] complex fp16 = 33.5 MB.
// Per-stage folded scales keep fp16 in range (applied at LOAD/prefilter so the
// fp16 LDS transpose midpoints also stay in range):
//   p1xz x1 (x-mid<=16, z-mid<=2k, out<=16k) -> p3y x2^-6 in prefilter (mid<=4k)
//   -> p45 x1 -> p6 x2^-8 at load (mid<=4k) -> p7 x2^-10 at load (mid<=1k)
//   == old 1/256^3 total.
static constexpr size_t VS   = 8388608;  // 128*256*256 per volume (A), elements
static constexpr int    ZSTR = 65536;    // 256*256
static constexpr int    YSTR = 256;
static constexpr size_t VSB  = 4194304;  // 128*256*128 per volume (B), elements
static constexpr int    BZS  = 32768;    // 256*128
static constexpr int    BYS  = 128;
static constexpr int    LSTR = 261;      // transpose-line stride; 261 mod 32 = 5 spreads banks
static constexpr int    PSTR = 260;      // plane row stride (u32); %4==0 for uint4, stride-260 col reads are 2-way (free)

typedef float vf2 __attribute__((ext_vector_type(2)));       // complex fp32 in regs
typedef _Float16 h2 __attribute__((ext_vector_type(2)));     // packed fp16 pair

// fp16 pack/unpack (v_cvt_f16_f32 RNE / v_cvt_f32_f16)
__device__ __forceinline__ unsigned pkh(vf2 a){
    h2 h; h.x = (_Float16)a.x; h.y = (_Float16)a.y;
    return __builtin_bit_cast(unsigned, h);
}
__device__ __forceinline__ vf2 uph(unsigned u){
    h2 h = __builtin_bit_cast(h2, u);
    vf2 r; r.x = (float)h.x; r.y = (float)h.y; return r;
}

__device__ __forceinline__ vf2 cmul(vf2 a, vf2 b){
    vf2 asw; asw.x = -a.y; asw.y = a.x;       // i*a
    return a*b.x + asw*b.y;                   // pk_mul + pk_fma
}

constexpr int BREV(int k){ return ((k&1)<<3)|((k&2)<<1)|((k&4)>>1)|((k&8)>>3); }

// Butterfly: a' = a+b; b' = (a-b) rotated by (c,s). Packed VOP3P.
__device__ __forceinline__ void bf(vf2& a, vf2& b, float c, float s){
    vf2 sum = a + b;
    vf2 dif = a - b;
    vf2 dsw; dsw.x = -dif.y; dsw.y = dif.x;   // i*dif
    b = dif*c + dsw*s;
    a = sum;
}

// Fully-unrolled 16-pt DIF FFT, natural input, bit-reversed output: X[k] = r[BREV(k)].
template<int DIR>
__device__ __forceinline__ void fft16(vf2 r[16]){
    constexpr float D = (float)DIR;
    constexpr float C16[8] = {1.f, 0.92387953f, 0.70710678f, 0.38268343f, 0.f, -0.38268343f, -0.70710678f, -0.92387953f};
    constexpr float S16[8] = {0.f, 0.38268343f, 0.70710678f, 0.92387953f, 1.f, 0.92387953f, 0.70710678f, 0.38268343f};
#pragma unroll
    for (int j = 0; j < 8; ++j) bf(r[j], r[j+8], C16[j], D*S16[j]);
    constexpr float C8[4] = {1.f, 0.70710678f, 0.f, -0.70710678f};
    constexpr float S8[4] = {0.f, 0.70710678f, 1.f, 0.70710678f};
#pragma unroll
    for (int g = 0; g < 16; g += 8)
#pragma unroll
        for (int j = 0; j < 4; ++j) bf(r[g+j], r[g+j+4], C8[j], D*S8[j]);
#pragma unroll
    for (int g = 0; g < 16; g += 4){
        bf(r[g],   r[g+2], 1.f, 0.f);
        bf(r[g+1], r[g+3], 0.f, D);
    }
#pragma unroll
    for (int g = 0; g < 16; g += 2) bf(r[g], r[g+1], 1.f, 0.f);
}

// Per-block twiddle table: tw[a*16+b] = e^{DIR*2pi*i*a*b/256}.
// Caller must barrier between init and first use. (Table beats a register
// recurrence on t-slow kernels: serial 15-cmul chain regressed in r5.)
__device__ __forceinline__ void init_tw(vf2* tw, float dir){
    int tid = threadIdx.x;
    float ang = dir * 0.0245436926f * (float)((tid >> 4)*(tid & 15));
    float s, c; __sincosf(ang, &s, &c);
    vf2 w; w.x = c; w.y = s;
    if (tid < 256) tw[tid] = w;
}

// TWO-COLUMN middle of four-step 256-pt FFT, t-SLOW layout (t = tid>>4).
// Packed fp16 LDS transpose buffer; 3 barriers, two passes (l<8 then l>=8).
// Range: inputs must be pre-scaled so |mid| <= 16*|in| < 65504.
template<int DIR>
__device__ __forceinline__ void mid256t2(vf2 r[2][16], unsigned* shp, const vf2* tw, int t, int l){
#pragma unroll
    for (int c = 0; c < 2; ++c) fft16<DIR>(r[c]);
#pragma unroll
    for (int k1 = 1; k1 < 16; ++k1){
        vf2 w = tw[k1*16 + t];                        // broadcast across l
        r[0][BREV(k1)] = cmul(r[0][BREV(k1)], w);
        r[1][BREV(k1)] = cmul(r[1][BREV(k1)], w);
    }
    int lr = l & 7;
    bool lo = (l < 8);
    if (lo){
#pragma unroll
        for (int c = 0; c < 2; ++c)
#pragma unroll
            for (int k1 = 0; k1 < 16; ++k1)
                shp[(lr*2 + c)*LSTR + k1*16 + (t ^ k1)] = pkh(r[c][BREV(k1)]);
    }
    __syncthreads();                      // W_lo before R_lo
    if (lo){
#pragma unroll
        for (int c = 0; c < 2; ++c)
#pragma unroll
            for (int n2 = 0; n2 < 16; ++n2)
                r[c][n2] = uph(shp[(lr*2 + c)*LSTR + t*16 + (n2 ^ t)]);
    }
    __syncthreads();                      // R_lo before W_hi (same lines)
    if (!lo){
#pragma unroll
        for (int c = 0; c < 2; ++c)
#pragma unroll
            for (int k1 = 0; k1 < 16; ++k1)
                shp[(lr*2 + c)*LSTR + k1*16 + (t ^ k1)] = pkh(r[c][BREV(k1)]);
    }
    __syncthreads();                      // W_hi before R_hi
    if (!lo){
#pragma unroll
        for (int c = 0; c < 2; ++c)
#pragma unroll
            for (int n2 = 0; n2 < 16; ++n2)
                r[c][n2] = uph(shp[(lr*2 + c)*LSTR + t*16 + (n2 ^ t)]);
    }
#pragma unroll
    for (int c = 0; c < 2; ++c) fft16<DIR>(r[c]);
}

// Register twiddle for the BARRIER-FREE t-fast paths (p1xz step 1 / p45, where
// load latency hides the serial chain): r[BREV(k1)] *= w^k1, w = e^{DIR*2pi*i*t/256}.
template<int DIR>
__device__ __forceinline__ void twiddle_reg(vf2 r[16], int t){
    float sn, cn; __sincosf((float)DIR * 0.0245436926f * (float)t, &sn, &cn);
    vf2 w; w.x = cn; w.y = sn;
    vf2 wk = w;
#pragma unroll
    for (int k1 = 1; k1 < 16; ++k1){
        r[BREV(k1)] = cmul(r[BREV(k1)], wk);
        wk = cmul(wk, w);
    }
}

// Intra-wave transpose core for the t-FAST layout (t = tid&15, l = tid>>4):
// transposes are INTRA-WAVE; lines l and l^2 time-share one LDS line in two
// phases; same-wave DS ops execute in issue order -> no s_barrier, but the
// phases must not be merged/reordered: sched_barrier(0) fences them and
// phase B iterates in reverse.
__device__ __forceinline__ void wave_transpose(vf2 r[16], vf2* shw, int t, int l){
    vf2* base = shw + ((l >> 2)*2 + (l & 1))*LSTR;        // line shared by l and l^2
    if ((l & 2) == 0){                                    // phase A: l_local 0,1
#pragma unroll
        for (int k1 = 0; k1 < 16; ++k1) base[k1*16 + (t ^ k1)] = r[BREV(k1)];
#pragma unroll
        for (int n2 = 0; n2 < 16; ++n2) r[n2] = base[t*16 + (n2 ^ t)];
    }
    __builtin_amdgcn_sched_barrier(0);                    // A-reads issue before B-writes
    if ((l & 2) != 0){                                    // phase B: l_local 2,3 (reverse order)
#pragma unroll
        for (int k1 = 15; k1 >= 0; --k1) base[k1*16 + (t ^ k1)] = r[BREV(k1)];
#pragma unroll
        for (int n2 = 15; n2 >= 0; --n2) r[n2] = base[t*16 + (n2 ^ t)];
    }
}

// Barrier-free mid256 (t-fast) with register twiddles: ZERO __syncthreads.
template<int DIR>
__device__ __forceinline__ void mid256wr(vf2 r[16], vf2* shw, int t, int l){
    fft16<DIR>(r);
    twiddle_reg<DIR>(r, t);
    wave_transpose(r, shw, t, l);
    fft16<DIR>(r);
}

// TWO-COLUMN strided-axis FFT on packed fp16: 32 consecutive x per block
// (2 per thread, uint2 = 128B/16 lanes). Reads idx<NIN (rest zero) scaled by
// insc at load (fold point for range safety); writes idx<NOUT unscaled.
template<int DIR, int NIN, int NOUT>
__device__ __forceinline__ void fft_strided2(unsigned* g, int S, float insc){
    __shared__ unsigned shp[16*LSTR];
    __shared__ vf2 tw[256];
    int t = threadIdx.x >> 4, l = threadIdx.x & 15;
    vf2 r[2][16];
    vf2 zero; zero.x = 0.f; zero.y = 0.f;
#pragma unroll
    for (int n1 = 0; n1 < 16; ++n1){
        if (n1 < NIN/16){
            uint2 ld = *reinterpret_cast<const uint2*>(&g[(size_t)(16*n1 + t)*S + 2*l]);
            r[0][n1] = uph(ld.x)*insc;
            r[1][n1] = uph(ld.y)*insc;
        } else { r[0][n1] = zero; r[1][n1] = zero; }
    }
    init_tw(tw, (float)DIR);
    __syncthreads();                                 // tw ready
    mid256t2<DIR>(r, shp, tw, t, l);
#pragma unroll
    for (int k2 = 0; k2 < 16; ++k2)
        if (k2 < NOUT/16){
            uint2 st; st.x = pkh(r[0][BREV(k2)]); st.y = pkh(r[1][BREV(k2)]);
            *reinterpret_cast<uint2*>(&g[(size_t)(t + 16*k2)*S + 2*l]) = st;
        }
}

// P1XZ: FUSED p1 + p2z. One (z<128, x:256) plane per block (fixed v, y<128),
// resident in LDS as packed fp16 (128 x PSTR u32 = 133 KB -> 1 block/CU,
// 512 threads = 8 waves). Step 1: per z-row, val = sqrt(relu(f*gz^2)),
// half-pixel x-average folded algebraically (prefilter + k=128 fixup, as the
// old p1), 256-pt x-FFT with IN-PLANE intra-wave transpose (per-wave DS
// ordering, no barriers). Step 2: per x-column, 256-pt z-FFT (z<128 in/out,
// as the old p2z), column inputs register-cached before one barrier so reads
// precede overwrites; shp wave-transpose. Step 3: stream plane -> A as uint4.
// Deletes p2z's entire 134 MB HBM round-trip.
__global__ void __launch_bounds__(512) k_p1xz(const float* __restrict__ in, unsigned* __restrict__ A){
    __shared__ unsigned plane[128*PSTR];             // [z][x] packed fp16
    __shared__ unsigned shp[16*LSTR];                // step-2 transpose lines
    __shared__ vf2 tw[256];
    int tid = threadIdx.x, bid = blockIdx.x;         // v*128 + y   (y < 128)
    int y = bid & 127, v = bid >> 7;
    init_tw(tw, -1.f);                               // used by step 2 (forward)
    int t = tid & 15, g = tid >> 4;                  // 32 groups of 16 lanes

    // ---- step 1: x-FFT rows z = g + 32*rr ----
    float valr[4][8];
#pragma unroll
    for (int rr = 0; rr < 4; ++rr){
        int z = g + 32*rr;
        const float* src = in + (size_t)(v*128 + z)*16384 + (size_t)y*128;
#pragma unroll
        for (int n1 = 0; n1 < 8; ++n1) valr[rr][n1] = src[16*n1 + t];   // all loads issue first
    }
    vf2 cp[8];                                       // prefilter coeffs (shared across rr)
#pragma unroll
    for (int n1 = 0; n1 < 8; ++n1){
        float sn, cn; __sincosf(0.0245436926f * (float)(16*n1 + t), &sn, &cn);
        cp[n1].x = 0.5f*(1.f + cn); cp[n1].y = 0.5f*sn;
    }
#pragma unroll
    for (int rr = 0; rr < 4; ++rr){
        int z = g + 32*rr;
        float gz = z * (1.0f/127.0f);
        float g2 = gz*gz;
        float val[8];
#pragma unroll
        for (int n1 = 0; n1 < 8; ++n1){
            float xv = valr[rr][n1] * g2;
            val[n1] = xv > 0.f ? sqrtf(xv) : 0.f;
        }
        // k=128 fixup: S = sum (-1)^n x[n]; sign=(-1)^t; xor 1/2/4/8 stays in 16-lane group
        float part = ((val[0]+val[1])+(val[2]+val[3]))+((val[4]+val[5])+(val[6]+val[7]));
        part = (t & 1) ? -part : part;
        part += __shfl_xor(part, 1);
        part += __shfl_xor(part, 2);
        part += __shfl_xor(part, 4);
        part += __shfl_xor(part, 8);
        vf2 r[16];
        vf2 zero; zero.x = 0.f; zero.y = 0.f;
#pragma unroll
        for (int n1 = 8; n1 < 16; ++n1) r[n1] = zero;
#pragma unroll
        for (int n1 = 0; n1 < 8; ++n1){ r[n1].x = val[n1]*cp[n1].x; r[n1].y = val[n1]*cp[n1].y; }
        fft16<-1>(r);
        twiddle_reg<-1>(r, t);
        unsigned* pr = plane + z*PSTR;
        // in-plane 16x16 transpose: reads follow writes in per-wave DS order;
        // memory aliasing (overlapping slot sets) keeps the compiler honest.
#pragma unroll
        for (int k1 = 0; k1 < 16; ++k1) pr[k1*16 + (t ^ k1)] = pkh(r[BREV(k1)]);
#pragma unroll
        for (int n2 = 0; n2 < 16; ++n2) r[n2] = uph(pr[t*16 + (n2 ^ t)]);
        fft16<-1>(r);
        if (t == 0){ r[1].x = part*0.5f; r[1].y = 0.f; }   // BREV(8)=1 -> X[128], real
#pragma unroll
        for (int k2 = 0; k2 < 16; ++k2) pr[t + 16*k2] = pkh(r[BREV(k2)]);
    }
    __syncthreads();                                 // plane (x-FFT'd) + tw ready

    // ---- step 2: z-FFT cols x = g + 32*cc; inputs cached, then barrier ----
    unsigned colin[8][8];                            // [cc][n1]
#pragma unroll
    for (int cc = 0; cc < 8; ++cc){
        int x = g + 32*cc;
#pragma unroll
        for (int n1 = 0; n1 < 8; ++n1)
            colin[cc][n1] = plane[(16*n1 + t)*PSTR + x];   // lanes read consecutive z: conflict-free
    }
    __syncthreads();                                 // all col reads before overwrites
#pragma unroll
    for (int cc = 0; cc < 8; ++cc){
        int x = g + 32*cc;
        vf2 r[16];
        vf2 zero; zero.x = 0.f; zero.y = 0.f;
#pragma unroll
        for (int n1 = 0; n1 < 8; ++n1) r[n1] = uph(colin[cc][n1]);
#pragma unroll
        for (int n1 = 8; n1 < 16; ++n1) r[n1] = zero;
        fft16<-1>(r);
#pragma unroll
        for (int k1 = 1; k1 < 16; ++k1)
            r[BREV(k1)] = cmul(r[BREV(k1)], tw[k1*16 + t]);
        // u32 wave-transpose via shp: per-wave 2 lines, 2 phases on (g&2)
        unsigned* sb = shp + ((g >> 2)*2 + (g & 1))*LSTR;
        if ((g & 2) == 0){
#pragma unroll
            for (int k1 = 0; k1 < 16; ++k1) sb[k1*16 + (t ^ k1)] = pkh(r[BREV(k1)]);
#pragma unroll
            for (int n2 = 0; n2 < 16; ++n2) r[n2] = uph(sb[t*16 + (n2 ^ t)]);
        }
        __builtin_amdgcn_sched_barrier(0);           // A-reads issue before B-writes
        if ((g & 2) != 0){
#pragma unroll
            for (int k1 = 15; k1 >= 0; --k1) sb[k1*16 + (t ^ k1)] = pkh(r[BREV(k1)]);
#pragma unroll
            for (int n2 = 15; n2 >= 0; --n2) r[n2] = uph(sb[t*16 + (n2 ^ t)]);
        }
        fft16<-1>(r);
#pragma unroll
        for (int k2 = 0; k2 < 8; ++k2)               // z = t+16*k2 < 128 only
            plane[(t + 16*k2)*PSTR + x] = pkh(r[BREV(k2)]);
    }
    __syncthreads();                                 // plane (z-FFT'd) ready

    // ---- step 3: stream plane -> A, uint4 coalesced ----
    unsigned* dstA = A + (size_t)v*VS + (size_t)y*YSTR;
#pragma unroll
    for (int i = 0; i < 16; ++i){
        int linear = (tid + 512*i)*4;                // 32768 u32 total
        int z = linear >> 8, x = linear & 255;       // x multiple of 4
        uint4 val = *reinterpret_cast<const uint4*>(&plane[z*PSTR + x]);
        *reinterpret_cast<uint4*>(&dstA[(size_t)z*ZSTR + x]) = val;
    }
}

// P3y: forward FFT along y for each z<128 slab (read y<128, write 256).
// Half-pixel y-average folded algebraically; 2^-6 scale folded into the
// PREFILTER so the fp16 LDS transpose midpoints stay in range (<=4k).
// 32 x per block (2/thread).
__global__ void __launch_bounds__(256) k_p3y(unsigned* __restrict__ A){
    __shared__ unsigned shp[16*LSTR];
    __shared__ vf2 tw[256];
    __shared__ vf2 shW[128];                         // per-wave partials, 2 cols
    const float SC3 = 0.015625f;                     // 2^-6
    int bid = blockIdx.x;                            // v*1024 + z*8 + xb   (z < 128)
    int xb = bid & 7, z = (bid >> 3) & 127, v = bid >> 10;
    unsigned* g = A + (size_t)v*VS + (size_t)z*ZSTR + xb*32;
    int t = threadIdx.x >> 4, l = threadIdx.x & 15;
    vf2 r[2][16];
    vf2 zero; zero.x = 0.f; zero.y = 0.f;
#pragma unroll
    for (int n1 = 0; n1 < 16; ++n1){
        if (n1 < 8){
            uint2 ld = *reinterpret_cast<const uint2*>(&g[(size_t)(16*n1 + t)*YSTR + 2*l]);
            r[0][n1] = uph(ld.x);
            r[1][n1] = uph(ld.y);
        } else { r[0][n1] = zero; r[1][n1] = zero; }
    }
    // alternating-sum partial from RAW inputs: (-1)^n = (-1)^t since 16*n1 even.
#pragma unroll
    for (int c = 0; c < 2; ++c){
        vf2 part = ((r[c][0]+r[c][1]) + (r[c][2]+r[c][3])) + ((r[c][4]+r[c][5]) + (r[c][6]+r[c][7]));
        part = part * ((t & 1) ? -1.f : 1.f);
        part.x += __shfl_xor(part.x, 16);            // t ^ 1  (within wave)
        part.y += __shfl_xor(part.y, 16);
        part.x += __shfl_xor(part.x, 32);            // t ^ 2  (within wave)
        part.y += __shfl_xor(part.y, 32);
        if ((t & 3) == 0) shW[(t >> 2)*32 + 2*l + c] = part;  // per (wave, col)
    }
    // cyclic-average pre-filter x SC3: r[n] *= SC3*0.5*(1 + e^{+2pi i n/256})
#pragma unroll
    for (int n1 = 0; n1 < 8; ++n1){
        float sn, cn; __sincosf(0.0245436926f * (float)(16*n1 + t), &sn, &cn);
        vf2 c; c.x = SC3*0.5f*(1.f + cn); c.y = SC3*0.5f*sn;
        r[0][n1] = cmul(r[0][n1], c);
        r[1][n1] = cmul(r[1][n1], c);
    }
    init_tw(tw, -1.f);
    __syncthreads();                                 // tw + shW ready
    mid256t2<-1>(r, shp, tw, t, l);
    if (t == 0){                                     // k = 128 fix-up (t=0, k2=8)
#pragma unroll
        for (int c = 0; c < 2; ++c){
            vf2 S = (shW[2*l + c] + shW[32 + 2*l + c]) + (shW[64 + 2*l + c] + shW[96 + 2*l + c]);
            r[c][BREV(8)] = S * (0.5f*SC3);
        }
    }
#pragma unroll
    for (int k2 = 0; k2 < 16; ++k2){                 // uint2 store: 16 lanes = 128B
        uint2 st; st.x = pkh(r[0][BREV(k2)]); st.y = pkh(r[1][BREV(k2)]);
        *reinterpret_cast<uint2*>(&g[(size_t)(t + 16*k2)*YSTR + 2*l]) = st;
    }
}

// P45: fused Stolt z-resample (2 taps) + x-iFFT. Direct global->register gather
// (t=tid&15 lane-fast) and direct register->global store. t-fast + register
// twiddles -> ZERO barriers. Gather-BW-bound (r5); unchanged.
__global__ void __launch_bounds__(256) k_p45(const unsigned* __restrict__ A, unsigned* __restrict__ B){
    __shared__ vf2 sh8[8*LSTR];
    int tid = threadIdx.x, bid = blockIdx.x;         // v*2048 + zn*16 + yc
    int yc = bid & 15, zn = (bid >> 4) & 127, v = bid >> 11;
    const unsigned* Av = A + (size_t)v*VS;
    int t = tid & 15, l = tid >> 4;                  // lanes 0..15 = consecutive x
    int yn = yc*16 + l;
    float gy = (yn < 128 ? yn : yn - 256) * (1.0f/128.0f);
    float gz = zn * (1.0f/128.0f);
    float c2 = 0.1024f*gy*gy + gz*gz;
    unsigned rowoff = (unsigned)yn*YSTR;
    vf2 r[16];
#pragma unroll
    for (int n1 = 0; n1 < 16; ++n1){
        int xn = 16*n1 + t;
        float gx = (xn < 128 ? xn : xn - 256) * (1.0f/128.0f);
        float s2 = c2 + 0.1024f*gx*gx;
        float rs = __builtin_amdgcn_rsqf(s2 + 1e-12f);   // 1/gznew; zn==0 row -> wf=0
        float gznew = s2 * rs;
        float pz = gznew*128.0f + 127.5f;
        int zi = (int)pz;                                // trunc == floor (pz>0)
        float dz = pz - (float)zi;
        int zp0 = zi - 128;                              // natural z of first tap
        float wf = gz * rs;                              // gz/gznew
        float w0 = (((unsigned)zp0     < 128u) ? (1.0f - dz) : 0.f) * wf;
        float w1 = (((unsigned)(zp0+1) < 128u) ? dz : 0.f) * wf;
        vf2 v0 = uph(Av[(size_t)((unsigned)(zp0 & 127) * ZSTR) + rowoff + xn]);
        vf2 v1 = uph(Av[(size_t)((unsigned)((zp0 + 1) & 127) * ZSTR) + rowoff + xn]);
        r[n1] = v0*w0 + v1*w1;
    }
    mid256wr<1>(r, sh8, t, l);
    unsigned* dst = B + (size_t)v*VSB + (size_t)zn*BZS + (size_t)yn*BYS;
#pragma unroll
    for (int k2 = 0; k2 < 8; ++k2)                   // x = t+16*k2 < 128, coalesced
        dst[t + 16*k2] = pkh(r[BREV(k2)]);
}

// P6: inverse FFT along y on packed B (x<128). Read 256 y, write y<128.
// 2^-8 scale folded at LOAD (fp16 LDS mid <=4k). 32 x per block (2/thread).
__global__ void __launch_bounds__(256) k_p6(unsigned* __restrict__ B){
    int bid = blockIdx.x;                            // v*512 + zn*4 + xb
    int xb = bid & 3, zn = (bid >> 2) & 127, v = bid >> 9;
    fft_strided2<1,256,128>(B + (size_t)v*VSB + (size_t)zn*BZS + xb*32, BYS, 0.00390625f);
}

// P7: inverse FFT along z for y<128, x<128 on packed B. Read zn<128 scaled by
// residual 2^-10 at load (total = 2^-24 = 1/256^3), write fp32 real out as
// float2 (2 adjacent x). 32 x per block (2/thread).
__global__ void __launch_bounds__(256) k_p7(const unsigned* __restrict__ B, float* __restrict__ out){
    __shared__ unsigned shp[16*LSTR];
    __shared__ vf2 tw[256];
    const float sc = 9.765625e-4f;                   // 2^-10
    int bid = blockIdx.x;                            // v*512 + y*4 + xb
    int xb = bid & 3, y = (bid >> 2) & 127, v = bid >> 9;
    const unsigned* g = B + (size_t)v*VSB + (size_t)y*BYS + xb*32;
    int t = threadIdx.x >> 4, l = threadIdx.x & 15;
    vf2 r[2][16];
    vf2 zero; zero.x = 0.f; zero.y = 0.f;
#pragma unroll
    for (int n1 = 0; n1 < 16; ++n1){
        if (n1 < 8){
            uint2 ld = *reinterpret_cast<const uint2*>(&g[(size_t)(16*n1 + t)*BZS + 2*l]);
            r[0][n1] = uph(ld.x)*sc;
            r[1][n1] = uph(ld.y)*sc;
        } else { r[0][n1] = zero; r[1][n1] = zero; }
    }
    init_tw(tw, 1.f);
    __syncthreads();
    mid256t2<1>(r, shp, tw, t, l);
    float* dst = out + ((size_t)(v*128)*128 + y)*128 + xb*32 + 2*l;
#pragma unroll
    for (int k2 = 0; k2 < 8; ++k2){                  // k = t + 16*k2 < 128
        float2 st; st.x = r[0][BREV(k2)].x; st.y = r[1][BREV(k2)].x;
        *reinterpret_cast<float2*>(&dst[(size_t)(t + 16*k2)*16384]) = st;
    }
}

extern "C" void kernel_launch(void* const* d_in, const int* in_sizes, int n_in,
                              void* d_out, int out_size, void* d_ws, size_t ws_size,
                              hipStream_t stream){
    const float* in = (const float*)d_in[0];
    float* out = (float*)d_out;
    unsigned* A = (unsigned*)d_ws;         // 67 MB (fp16-packed)
    unsigned* B = A + 2*VS;                // 33.5 MB (fp16-packed)
    k_p1xz<<<  256, 512, 0, stream>>>(in, A);   // fused x-FFT + z-FFT (plane in LDS)
    k_p3y <<< 2048, 256, 0, stream>>>(A);
    k_p45 <<< 4096, 256, 0, stream>>>(A, B);
    k_p6  <<< 1024, 256, 0, stream>>>(B);
    k_p7  <<< 1024, 256, 0, stream>>>(B, out);
}

// Round 10
// 184.900 us; speedup vs baseline: 1.0170x; 1.0170x over previous
//
#include <hip/hip_runtime.h>

// Geometry: M=N=128, padded S=256. Two volumes (b*d=2).
// A: [v][z<128][y:256][x:256] complex FP16-PACKED (uint32 = re:f16 | im:f16<<16) = 67 MB.
// B (packed): [v][z<128][y:256][x<128] complex fp16 = 33.5 MB.
// Per-stage folded scales keep fp16 in range (applied at LOAD/prefilter so the
// fp16 LDS transpose midpoints (<=16x input) also stay in range):
//   p1 x1 (<=128) -> p2z x1 (mid<=2k) -> p3y x2^-6 in prefilter (mid<=4k)
//   -> p45 x1 -> p6 x2^-8 at load (mid<=4k) -> p7 x2^-10 at load (mid<=1k)
//   == old 1/256^3 total.
// r9 lesson: fusing p1+p2z into one LDS-plane kernel LOSES (~43.5 vs 38.8 us):
// 133 KB plane -> 1 block/CU -> latency trap; redundancy fixes hit a VALU floor.
static constexpr size_t VS   = 8388608;  // 128*256*256 per volume (A), elements
static constexpr int    ZSTR = 65536;    // 256*256
static constexpr int    YSTR = 256;
static constexpr size_t VSB  = 4194304;  // 128*256*128 per volume (B), elements
static constexpr int    BZS  = 32768;    // 256*128
static constexpr int    BYS  = 128;
static constexpr int    LSTR = 261;      // LDS line stride; 261 mod 32 = 5 spreads banks

typedef float vf2 __attribute__((ext_vector_type(2)));       // complex fp32 in regs
typedef _Float16 h2 __attribute__((ext_vector_type(2)));     // packed fp16 pair

// fp16 pack/unpack (v_cvt_f16_f32 RNE / v_cvt_f32_f16)
__device__ __forceinline__ unsigned pkh(vf2 a){
    h2 h; h.x = (_Float16)a.x; h.y = (_Float16)a.y;
    return __builtin_bit_cast(unsigned, h);
}
__device__ __forceinline__ vf2 uph(unsigned u){
    h2 h = __builtin_bit_cast(h2, u);
    vf2 r; r.x = (float)h.x; r.y = (float)h.y; return r;
}

__device__ __forceinline__ vf2 cmul(vf2 a, vf2 b){
    vf2 asw; asw.x = -a.y; asw.y = a.x;       // i*a
    return a*b.x + asw*b.y;                   // pk_mul + pk_fma
}

constexpr int BREV(int k){ return ((k&1)<<3)|((k&2)<<1)|((k&4)>>1)|((k&8)>>3); }

// Butterfly: a' = a+b; b' = (a-b) rotated by (c,s). Packed VOP3P.
__device__ __forceinline__ void bf(vf2& a, vf2& b, float c, float s){
    vf2 sum = a + b;
    vf2 dif = a - b;
    vf2 dsw; dsw.x = -dif.y; dsw.y = dif.x;   // i*dif
    b = dif*c + dsw*s;
    a = sum;
}

// Fully-unrolled 16-pt DIF FFT, natural input, bit-reversed output: X[k] = r[BREV(k)].
template<int DIR>
__device__ __forceinline__ void fft16(vf2 r[16]){
    constexpr float D = (float)DIR;
    constexpr float C16[8] = {1.f, 0.92387953f, 0.70710678f, 0.38268343f, 0.f, -0.38268343f, -0.70710678f, -0.92387953f};
    constexpr float S16[8] = {0.f, 0.38268343f, 0.70710678f, 0.92387953f, 1.f, 0.92387953f, 0.70710678f, 0.38268343f};
#pragma unroll
    for (int j = 0; j < 8; ++j) bf(r[j], r[j+8], C16[j], D*S16[j]);
    constexpr float C8[4] = {1.f, 0.70710678f, 0.f, -0.70710678f};
    constexpr float S8[4] = {0.f, 0.70710678f, 1.f, 0.70710678f};
#pragma unroll
    for (int g = 0; g < 16; g += 8)
#pragma unroll
        for (int j = 0; j < 4; ++j) bf(r[g+j], r[g+j+4], C8[j], D*S8[j]);
#pragma unroll
    for (int g = 0; g < 16; g += 4){
        bf(r[g],   r[g+2], 1.f, 0.f);
        bf(r[g+1], r[g+3], 0.f, D);
    }
#pragma unroll
    for (int g = 0; g < 16; g += 2) bf(r[g], r[g+1], 1.f, 0.f);
}

// Per-block twiddle table: tw[a*16+b] = e^{DIR*2pi*i*a*b/256}.
// Caller must barrier between init and first use. (Table beats a register
// recurrence on t-slow kernels: serial 15-cmul chain regressed in r5.)
__device__ __forceinline__ void init_tw(vf2* tw, float dir){
    int tid = threadIdx.x;
    float ang = dir * 0.0245436926f * (float)((tid >> 4)*(tid & 15));
    float s, c; __sincosf(ang, &s, &c);
    vf2 w; w.x = c; w.y = s;
    tw[tid] = w;
}

// TWO-COLUMN middle of four-step 256-pt FFT, t-SLOW layout (t = tid>>4).
// Each thread carries 2 x-columns; the 16x16 transposes go through a PACKED
// fp16 LDS buffer (16 lines x u32 = 16.7 KB, same footprint as the old fp32
// 8-line buffer). 3 barriers, two passes (l<8 then l>=8), 16 lines per pass.
// Range: inputs must be pre-scaled so |mid| <= 16*|in| < 65504.
template<int DIR>
__device__ __forceinline__ void mid256t2(vf2 r[2][16], unsigned* shp, const vf2* tw, int t, int l){
#pragma unroll
    for (int c = 0; c < 2; ++c) fft16<DIR>(r[c]);
#pragma unroll
    for (int k1 = 1; k1 < 16; ++k1){
        vf2 w = tw[k1*16 + t];                        // broadcast across l
        r[0][BREV(k1)] = cmul(r[0][BREV(k1)], w);
        r[1][BREV(k1)] = cmul(r[1][BREV(k1)], w);
    }
    int lr = l & 7;
    bool lo = (l < 8);
    if (lo){
#pragma unroll
        for (int c = 0; c < 2; ++c)
#pragma unroll
            for (int k1 = 0; k1 < 16; ++k1)
                shp[(lr*2 + c)*LSTR + k1*16 + (t ^ k1)] = pkh(r[c][BREV(k1)]);
    }
    __syncthreads();                      // W_lo before R_lo
    if (lo){
#pragma unroll
        for (int c = 0; c < 2; ++c)
#pragma unroll
            for (int n2 = 0; n2 < 16; ++n2)
                r[c][n2] = uph(shp[(lr*2 + c)*LSTR + t*16 + (n2 ^ t)]);
    }
    __syncthreads();                      // R_lo before W_hi (same lines)
    if (!lo){
#pragma unroll
        for (int c = 0; c < 2; ++c)
#pragma unroll
            for (int k1 = 0; k1 < 16; ++k1)
                shp[(lr*2 + c)*LSTR + k1*16 + (t ^ k1)] = pkh(r[c][BREV(k1)]);
    }
    __syncthreads();                      // W_hi before R_hi
    if (!lo){
#pragma unroll
        for (int c = 0; c < 2; ++c)
#pragma unroll
            for (int n2 = 0; n2 < 16; ++n2)
                r[c][n2] = uph(shp[(lr*2 + c)*LSTR + t*16 + (n2 ^ t)]);
    }
#pragma unroll
    for (int c = 0; c < 2; ++c) fft16<DIR>(r[c]);
}

// Register twiddle for the BARRIER-FREE t-fast path only (p1/p45, where gather
// latency hides the serial chain): r[BREV(k1)] *= w^k1, w = e^{DIR*2pi*i*t/256}.
template<int DIR>
__device__ __forceinline__ void twiddle_reg(vf2 r[16], int t){
    float sn, cn; __sincosf((float)DIR * 0.0245436926f * (float)t, &sn, &cn);
    vf2 w; w.x = cn; w.y = sn;
    vf2 wk = w;
#pragma unroll
    for (int k1 = 1; k1 < 16; ++k1){
        r[BREV(k1)] = cmul(r[BREV(k1)], wk);
        wk = cmul(wk, w);
    }
}

// Intra-wave transpose core for the t-FAST layout (t = tid&15, l = tid>>4):
// transposes are INTRA-WAVE; lines l and l^2 time-share one LDS line in two
// phases; same-wave DS ops execute in issue order -> no s_barrier, but the
// phases must not be merged/reordered: sched_barrier(0) fences them and
// phase B iterates in reverse.
__device__ __forceinline__ void wave_transpose(vf2 r[16], vf2* shw, int t, int l){
    vf2* base = shw + ((l >> 2)*2 + (l & 1))*LSTR;        // line shared by l and l^2
    if ((l & 2) == 0){                                    // phase A: l_local 0,1
#pragma unroll
        for (int k1 = 0; k1 < 16; ++k1) base[k1*16 + (t ^ k1)] = r[BREV(k1)];
#pragma unroll
        for (int n2 = 0; n2 < 16; ++n2) r[n2] = base[t*16 + (n2 ^ t)];
    }
    __builtin_amdgcn_sched_barrier(0);                    // A-reads issue before B-writes
    if ((l & 2) != 0){                                    // phase B: l_local 2,3 (reverse order)
#pragma unroll
        for (int k1 = 15; k1 >= 0; --k1) base[k1*16 + (t ^ k1)] = r[BREV(k1)];
#pragma unroll
        for (int n2 = 15; n2 >= 0; --n2) r[n2] = base[t*16 + (n2 ^ t)];
    }
}

// Barrier-free mid256 (t-fast) with register twiddles: ZERO __syncthreads.
template<int DIR>
__device__ __forceinline__ void mid256wr(vf2 r[16], vf2* shw, int t, int l){
    fft16<DIR>(r);
    twiddle_reg<DIR>(r, t);
    wave_transpose(r, shw, t, l);
    fft16<DIR>(r);
}

// TWO-COLUMN strided-axis FFT on packed fp16: 32 consecutive x per block
// (2 per thread, uint2 = 128B/16 lanes). Reads idx<NIN (rest zero) scaled by
// insc at load (fold point for range safety); writes idx<NOUT unscaled.
template<int DIR, int NIN, int NOUT>
__device__ __forceinline__ void fft_strided2(unsigned* g, int S, float insc){
    __shared__ unsigned shp[16*LSTR];
    __shared__ vf2 tw[256];
    int t = threadIdx.x >> 4, l = threadIdx.x & 15;
    vf2 r[2][16];
    vf2 zero; zero.x = 0.f; zero.y = 0.f;
#pragma unroll
    for (int n1 = 0; n1 < 16; ++n1){
        if (n1 < NIN/16){
            uint2 ld = *reinterpret_cast<const uint2*>(&g[(size_t)(16*n1 + t)*S + 2*l]);
            r[0][n1] = uph(ld.x)*insc;
            r[1][n1] = uph(ld.y)*insc;
        } else { r[0][n1] = zero; r[1][n1] = zero; }
    }
    init_tw(tw, (float)DIR);
    __syncthreads();                                 // tw ready
    mid256t2<DIR>(r, shp, tw, t, l);
#pragma unroll
    for (int k2 = 0; k2 < 16; ++k2)
        if (k2 < NOUT/16){
            uint2 st; st.x = pkh(r[0][BREV(k2)]); st.y = pkh(r[1][BREV(k2)]);
            *reinterpret_cast<uint2*>(&g[(size_t)(t + 16*k2)*S + 2*l]) = st;
        }
}

// P1: read input, val = sqrt(relu(f*gz^2)), zero-pad 128->256, forward FFT along x
// with the half-pixel x-average folded ALGEBRAICALLY:
//   out[k] = FFT( x[n] * 0.5*(1 + e^{+2pi i n/256}) )[k]   (cyclic part)
//   out[128] = 0.5 * sum_n (-1)^n x[n]                      (dropped tap at k=128)
// t-FAST layout, mid256wr, ZERO __syncthreads. Stores fp16-packed A (scale 1).
__global__ void __launch_bounds__(256) k_p1(const float* __restrict__ in, unsigned* __restrict__ A){
    __shared__ vf2 sh8[8*LSTR];
    int tid = threadIdx.x, bid = blockIdx.x;         // v*1024 + z*8 + yc
    int yc = bid & 7, z = (bid >> 3) & 127, v = bid >> 10;
    int t = tid & 15, l = tid >> 4;                  // lanes 0..15 = consecutive x
    float gz = z * (1.0f/127.0f);
    float g2 = gz*gz;
    const float* src = in + (((size_t)(v*128 + z))*128 + yc*16 + l)*128;  // row y=yc*16+l
    float val[8];
#pragma unroll
    for (int n1 = 0; n1 < 8; ++n1) val[n1] = src[16*n1 + t];   // loads issue first
#pragma unroll
    for (int n1 = 0; n1 < 8; ++n1){
        float x = val[n1] * g2;
        val[n1] = x > 0.f ? sqrtf(x) : 0.f;
    }
    // k=128 fix-up: S = sum_n (-1)^n x[n]; sign = (-1)^t. Intra-row butterfly over t.
    float part = ((val[0]+val[1]) + (val[2]+val[3])) + ((val[4]+val[5]) + (val[6]+val[7]));
    part = (t & 1) ? -part : part;
    part += __shfl_xor(part, 1);
    part += __shfl_xor(part, 2);
    part += __shfl_xor(part, 4);
    part += __shfl_xor(part, 8);
    // prefilter (input real): r[n] = x[n] * 0.5*(1+cos, sin), theta = 2pi n/256
    vf2 r[16];
    vf2 zero; zero.x = 0.f; zero.y = 0.f;
#pragma unroll
    for (int n1 = 8; n1 < 16; ++n1) r[n1] = zero;
#pragma unroll
    for (int n1 = 0; n1 < 8; ++n1){
        float sn, cn; __sincosf(0.0245436926f * (float)(16*n1 + t), &sn, &cn);
        r[n1].x = val[n1] * 0.5f * (1.f + cn);
        r[n1].y = val[n1] * 0.5f * sn;
    }
    mid256wr<-1>(r, sh8, t, l);
    if (t == 0){ r[1].x = part*0.5f; r[1].y = 0.f; } // BREV(8)=1 -> X[128], real
    unsigned* dst = A + (size_t)v*VS + (size_t)z*ZSTR + (size_t)(yc*16 + l)*YSTR;
#pragma unroll
    for (int k2 = 0; k2 < 16; ++k2)                  // x = t+16*k2, 16 lanes = 64B
        dst[t + 16*k2] = pkh(r[BREV(k2)]);
}

// P2z: forward FFT along z (before y-FFT: only y<128 columns exist -> half
// traffic). Read z<128, write z<128. In-place, scale 1 (mid<=2k, fp16-safe).
// 32 x per block (2/thread).
__global__ void __launch_bounds__(256) k_p2z(unsigned* __restrict__ A){
    int bid = blockIdx.x;                            // v*1024 + y*8 + xb   (y < 128)
    int xb = bid & 7, y = (bid >> 3) & 127, v = bid >> 10;
    fft_strided2<-1,128,128>(A + (size_t)v*VS + (size_t)y*YSTR + xb*32, ZSTR, 1.f);
}

// P3y: forward FFT along y for each z<128 slab (read y<128, write 256).
// Half-pixel y-average folded algebraically; 2^-6 scale folded into the
// PREFILTER so the fp16 LDS transpose midpoints stay in range (<=4k).
// 32 x per block (2/thread).
__global__ void __launch_bounds__(256) k_p3y(unsigned* __restrict__ A){
    __shared__ unsigned shp[16*LSTR];
    __shared__ vf2 tw[256];
    __shared__ vf2 shW[128];                         // per-wave partials, 2 cols
    const float SC3 = 0.015625f;                     // 2^-6
    int bid = blockIdx.x;                            // v*1024 + z*8 + xb   (z < 128)
    int xb = bid & 7, z = (bid >> 3) & 127, v = bid >> 10;
    unsigned* g = A + (size_t)v*VS + (size_t)z*ZSTR + xb*32;
    int t = threadIdx.x >> 4, l = threadIdx.x & 15;
    vf2 r[2][16];
    vf2 zero; zero.x = 0.f; zero.y = 0.f;
#pragma unroll
    for (int n1 = 0; n1 < 16; ++n1){
        if (n1 < 8){
            uint2 ld = *reinterpret_cast<const uint2*>(&g[(size_t)(16*n1 + t)*YSTR + 2*l]);
            r[0][n1] = uph(ld.x);
            r[1][n1] = uph(ld.y);
        } else { r[0][n1] = zero; r[1][n1] = zero; }
    }
    // alternating-sum partial from RAW inputs: (-1)^n = (-1)^t since 16*n1 even.
#pragma unroll
    for (int c = 0; c < 2; ++c){
        vf2 part = ((r[c][0]+r[c][1]) + (r[c][2]+r[c][3])) + ((r[c][4]+r[c][5]) + (r[c][6]+r[c][7]));
        part = part * ((t & 1) ? -1.f : 1.f);
        part.x += __shfl_xor(part.x, 16);            // t ^ 1  (within wave)
        part.y += __shfl_xor(part.y, 16);
        part.x += __shfl_xor(part.x, 32);            // t ^ 2  (within wave)
        part.y += __shfl_xor(part.y, 32);
        if ((t & 3) == 0) shW[(t >> 2)*32 + 2*l + c] = part;  // per (wave, col)
    }
    // cyclic-average pre-filter x SC3: r[n] *= SC3*0.5*(1 + e^{+2pi i n/256})
#pragma unroll
    for (int n1 = 0; n1 < 8; ++n1){
        float sn, cn; __sincosf(0.0245436926f * (float)(16*n1 + t), &sn, &cn);
        vf2 c; c.x = SC3*0.5f*(1.f + cn); c.y = SC3*0.5f*sn;
        r[0][n1] = cmul(r[0][n1], c);
        r[1][n1] = cmul(r[1][n1], c);
    }
    init_tw(tw, -1.f);
    __syncthreads();                                 // tw + shW ready
    mid256t2<-1>(r, shp, tw, t, l);
    if (t == 0){                                     // k = 128 fix-up (t=0, k2=8)
#pragma unroll
        for (int c = 0; c < 2; ++c){
            vf2 S = (shW[2*l + c] + shW[32 + 2*l + c]) + (shW[64 + 2*l + c] + shW[96 + 2*l + c]);
            r[c][BREV(8)] = S * (0.5f*SC3);
        }
    }
#pragma unroll
    for (int k2 = 0; k2 < 16; ++k2){                 // uint2 store: 16 lanes = 128B
        uint2 st; st.x = pkh(r[0][BREV(k2)]); st.y = pkh(r[1][BREV(k2)]);
        *reinterpret_cast<uint2*>(&g[(size_t)(t + 16*k2)*YSTR + 2*l]) = st;
    }
}

// P45: fused Stolt z-resample (2 taps) + x-iFFT. Direct global->register gather
// (t=tid&15 lane-fast) and direct register->global store. t-fast + register
// twiddles -> ZERO barriers. Gather-BW-bound (r5); unchanged.
__global__ void __launch_bounds__(256) k_p45(const unsigned* __restrict__ A, unsigned* __restrict__ B){
    __shared__ vf2 sh8[8*LSTR];
    int tid = threadIdx.x, bid = blockIdx.x;         // v*2048 + zn*16 + yc
    int yc = bid & 15, zn = (bid >> 4) & 127, v = bid >> 11;
    const unsigned* Av = A + (size_t)v*VS;
    int t = tid & 15, l = tid >> 4;                  // lanes 0..15 = consecutive x
    int yn = yc*16 + l;
    float gy = (yn < 128 ? yn : yn - 256) * (1.0f/128.0f);
    float gz = zn * (1.0f/128.0f);
    float c2 = 0.1024f*gy*gy + gz*gz;
    unsigned rowoff = (unsigned)yn*YSTR;
    vf2 r[16];
#pragma unroll
    for (int n1 = 0; n1 < 16; ++n1){
        int xn = 16*n1 + t;
        float gx = (xn < 128 ? xn : xn - 256) * (1.0f/128.0f);
        float s2 = c2 + 0.1024f*gx*gx;
        float rs = __builtin_amdgcn_rsqf(s2 + 1e-12f);   // 1/gznew; zn==0 row -> wf=0
        float gznew = s2 * rs;
        float pz = gznew*128.0f + 127.5f;
        int zi = (int)pz;                                // trunc == floor (pz>0)
        float dz = pz - (float)zi;
        int zp0 = zi - 128;                              // natural z of first tap
        float wf = gz * rs;                              // gz/gznew
        float w0 = (((unsigned)zp0     < 128u) ? (1.0f - dz) : 0.f) * wf;
        float w1 = (((unsigned)(zp0+1) < 128u) ? dz : 0.f) * wf;
        vf2 v0 = uph(Av[(size_t)((unsigned)(zp0 & 127) * ZSTR) + rowoff + xn]);
        vf2 v1 = uph(Av[(size_t)((unsigned)((zp0 + 1) & 127) * ZSTR) + rowoff + xn]);
        r[n1] = v0*w0 + v1*w1;
    }
    mid256wr<1>(r, sh8, t, l);
    unsigned* dst = B + (size_t)v*VSB + (size_t)zn*BZS + (size_t)yn*BYS;
#pragma unroll
    for (int k2 = 0; k2 < 8; ++k2)                   // x = t+16*k2 < 128, coalesced
        dst[t + 16*k2] = pkh(r[BREV(k2)]);
}

// P6: inverse FFT along y on packed B (x<128). Read 256 y, write y<128.
// 2^-8 scale folded at LOAD (fp16 LDS mid <=4k). 32 x per block (2/thread).
__global__ void __launch_bounds__(256) k_p6(unsigned* __restrict__ B){
    int bid = blockIdx.x;                            // v*512 + zn*4 + xb
    int xb = bid & 3, zn = (bid >> 2) & 127, v = bid >> 9;
    fft_strided2<1,256,128>(B + (size_t)v*VSB + (size_t)zn*BZS + xb*32, BYS, 0.00390625f);
}

// P7: inverse FFT along z for y<128, x<128 on packed B. Read zn<128 scaled by
// residual 2^-10 at load (total = 2^-24 = 1/256^3), write fp32 real out as
// float2 (2 adjacent x). 32 x per block (2/thread).
__global__ void __launch_bounds__(256) k_p7(const unsigned* __restrict__ B, float* __restrict__ out){
    __shared__ unsigned shp[16*LSTR];
    __shared__ vf2 tw[256];
    const float sc = 9.765625e-4f;                   // 2^-10
    int bid = blockIdx.x;                            // v*512 + y*4 + xb
    int xb = bid & 3, y = (bid >> 2) & 127, v = bid >> 9;
    const unsigned* g = B + (size_t)v*VSB + (size_t)y*BYS + xb*32;
    int t = threadIdx.x >> 4, l = threadIdx.x & 15;
    vf2 r[2][16];
    vf2 zero; zero.x = 0.f; zero.y = 0.f;
#pragma unroll
    for (int n1 = 0; n1 < 16; ++n1){
        if (n1 < 8){
            uint2 ld = *reinterpret_cast<const uint2*>(&g[(size_t)(16*n1 + t)*BZS + 2*l]);
            r[0][n1] = uph(ld.x)*sc;
            r[1][n1] = uph(ld.y)*sc;
        } else { r[0][n1] = zero; r[1][n1] = zero; }
    }
    init_tw(tw, 1.f);
    __syncthreads();
    mid256t2<1>(r, shp, tw, t, l);
    float* dst = out + ((size_t)(v*128)*128 + y)*128 + xb*32 + 2*l;
#pragma unroll
    for (int k2 = 0; k2 < 8; ++k2){                  // k = t + 16*k2 < 128
        float2 st; st.x = r[0][BREV(k2)].x; st.y = r[1][BREV(k2)].x;
        *reinterpret_cast<float2*>(&dst[(size_t)(t + 16*k2)*16384]) = st;
    }
}

extern "C" void kernel_launch(void* const* d_in, const int* in_sizes, int n_in,
                              void* d_out, int out_size, void* d_ws, size_t ws_size,
                              hipStream_t stream){
    const float* in = (const float*)d_in[0];
    float* out = (float*)d_out;
    unsigned* A = (unsigned*)d_ws;         // 67 MB (fp16-packed)
    unsigned* B = A + 2*VS;                // 33.5 MB (fp16-packed)
    k_p1 <<< 2048, 256, 0, stream>>>(in, A);
    k_p2z<<< 2048, 256, 0, stream>>>(A);   // z-FFT first: y<128 -> half traffic
    k_p3y<<< 2048, 256, 0, stream>>>(A);
    k_p45<<< 4096, 256, 0, stream>>>(A, B);
    k_p6 <<< 1024, 256, 0, stream>>>(B);
    k_p7 <<< 1024, 256, 0, stream>>>(B, out);
}

// Round 11
// 184.430 us; speedup vs baseline: 1.0196x; 1.0025x over previous
//
#include <hip/hip_runtime.h>

// Geometry: M=N=128, padded S=256. Two volumes (b*d=2).
// A: [v][z<128][y:256][x:256] complex FP16-PACKED (uint32 = re:f16 | im:f16<<16) = 67 MB.
// B (packed): [v][z<128][y:256][x<128] complex fp16 = 33.5 MB.
// Per-stage folded scales keep fp16 in range (applied at LOAD/prefilter so the
// fp16 LDS transpose midpoints (<=16x input) also stay in range):
//   p1 x1 (<=128) -> p2z x1 (mid<=2k) -> p3y x2^-6 in prefilter (mid<=4k)
//   -> p45 x1 -> p6 x2^-8 at load (mid<=4k) -> p7 x2^-10 at load (mid<=1k)
//   == old 1/256^3 total.
// r9 lesson: fusing p1+p2z into one LDS-plane kernel LOSES (~43.5 vs 38.8 us):
// 133 KB plane -> 1 block/CU -> latency trap; redundancy fixes hit a VALU floor.
static constexpr size_t VS   = 8388608;  // 128*256*256 per volume (A), elements
static constexpr int    ZSTR = 65536;    // 256*256
static constexpr int    YSTR = 256;
static constexpr size_t VSB  = 4194304;  // 128*256*128 per volume (B), elements
static constexpr int    BZS  = 32768;    // 256*128
static constexpr int    BYS  = 128;
static constexpr int    LSTR = 261;      // LDS line stride; 261 mod 32 = 5 spreads banks

typedef float vf2 __attribute__((ext_vector_type(2)));       // complex fp32 in regs
typedef _Float16 h2 __attribute__((ext_vector_type(2)));     // packed fp16 pair

// fp16 pack/unpack (v_cvt_f16_f32 RNE / v_cvt_f32_f16)
__device__ __forceinline__ unsigned pkh(vf2 a){
    h2 h; h.x = (_Float16)a.x; h.y = (_Float16)a.y;
    return __builtin_bit_cast(unsigned, h);
}
__device__ __forceinline__ vf2 uph(unsigned u){
    h2 h = __builtin_bit_cast(h2, u);
    vf2 r; r.x = (float)h.x; r.y = (float)h.y; return r;
}

__device__ __forceinline__ vf2 cmul(vf2 a, vf2 b){
    vf2 asw; asw.x = -a.y; asw.y = a.x;       // i*a
    return a*b.x + asw*b.y;                   // pk_mul + pk_fma
}

constexpr int BREV(int k){ return ((k&1)<<3)|((k&2)<<1)|((k&4)>>1)|((k&8)>>3); }

// Butterfly: a' = a+b; b' = (a-b) rotated by (c,s). Packed VOP3P.
__device__ __forceinline__ void bf(vf2& a, vf2& b, float c, float s){
    vf2 sum = a + b;
    vf2 dif = a - b;
    vf2 dsw; dsw.x = -dif.y; dsw.y = dif.x;   // i*dif
    b = dif*c + dsw*s;
    a = sum;
}

// Fully-unrolled 16-pt DIF FFT, natural input, bit-reversed output: X[k] = r[BREV(k)].
template<int DIR>
__device__ __forceinline__ void fft16(vf2 r[16]){
    constexpr float D = (float)DIR;
    constexpr float C16[8] = {1.f, 0.92387953f, 0.70710678f, 0.38268343f, 0.f, -0.38268343f, -0.70710678f, -0.92387953f};
    constexpr float S16[8] = {0.f, 0.38268343f, 0.70710678f, 0.92387953f, 1.f, 0.92387953f, 0.70710678f, 0.38268343f};
#pragma unroll
    for (int j = 0; j < 8; ++j) bf(r[j], r[j+8], C16[j], D*S16[j]);
    constexpr float C8[4] = {1.f, 0.70710678f, 0.f, -0.70710678f};
    constexpr float S8[4] = {0.f, 0.70710678f, 1.f, 0.70710678f};
#pragma unroll
    for (int g = 0; g < 16; g += 8)
#pragma unroll
        for (int j = 0; j < 4; ++j) bf(r[g+j], r[g+j+4], C8[j], D*S8[j]);
#pragma unroll
    for (int g = 0; g < 16; g += 4){
        bf(r[g],   r[g+2], 1.f, 0.f);
        bf(r[g+1], r[g+3], 0.f, D);
    }
#pragma unroll
    for (int g = 0; g < 16; g += 2) bf(r[g], r[g+1], 1.f, 0.f);
}

// Per-block twiddle table: tw[a*16+b] = e^{DIR*2pi*i*a*b/256}.
// Caller must barrier between init and first use. (Table beats a register
// recurrence on t-slow kernels: serial 15-cmul chain regressed in r5.)
__device__ __forceinline__ void init_tw(vf2* tw, float dir){
    int tid = threadIdx.x;
    float ang = dir * 0.0245436926f * (float)((tid >> 4)*(tid & 15));
    float s, c; __sincosf(ang, &s, &c);
    vf2 w; w.x = c; w.y = s;
    tw[tid] = w;
}

// TWO-COLUMN middle of four-step 256-pt FFT, t-SLOW layout (t = tid>>4).
// Each thread carries 2 x-columns; the 16x16 transposes go through a PACKED
// fp16 LDS buffer (16 lines x u32 = 16.7 KB). 3 barriers, two passes.
// Range: inputs must be pre-scaled so |mid| <= 16*|in| < 65504.
template<int DIR>
__device__ __forceinline__ void mid256t2(vf2 r[2][16], unsigned* shp, const vf2* tw, int t, int l){
#pragma unroll
    for (int c = 0; c < 2; ++c) fft16<DIR>(r[c]);
#pragma unroll
    for (int k1 = 1; k1 < 16; ++k1){
        vf2 w = tw[k1*16 + t];                        // broadcast across l
        r[0][BREV(k1)] = cmul(r[0][BREV(k1)], w);
        r[1][BREV(k1)] = cmul(r[1][BREV(k1)], w);
    }
    int lr = l & 7;
    bool lo = (l < 8);
    if (lo){
#pragma unroll
        for (int c = 0; c < 2; ++c)
#pragma unroll
            for (int k1 = 0; k1 < 16; ++k1)
                shp[(lr*2 + c)*LSTR + k1*16 + (t ^ k1)] = pkh(r[c][BREV(k1)]);
    }
    __syncthreads();                      // W_lo before R_lo
    if (lo){
#pragma unroll
        for (int c = 0; c < 2; ++c)
#pragma unroll
            for (int n2 = 0; n2 < 16; ++n2)
                r[c][n2] = uph(shp[(lr*2 + c)*LSTR + t*16 + (n2 ^ t)]);
    }
    __syncthreads();                      // R_lo before W_hi (same lines)
    if (!lo){
#pragma unroll
        for (int c = 0; c < 2; ++c)
#pragma unroll
            for (int k1 = 0; k1 < 16; ++k1)
                shp[(lr*2 + c)*LSTR + k1*16 + (t ^ k1)] = pkh(r[c][BREV(k1)]);
    }
    __syncthreads();                      // W_hi before R_hi
    if (!lo){
#pragma unroll
        for (int c = 0; c < 2; ++c)
#pragma unroll
            for (int n2 = 0; n2 < 16; ++n2)
                r[c][n2] = uph(shp[(lr*2 + c)*LSTR + t*16 + (n2 ^ t)]);
    }
#pragma unroll
    for (int c = 0; c < 2; ++c) fft16<DIR>(r[c]);
}

// Register twiddle for the BARRIER-FREE t-fast path only (p1/p45, where gather
// latency hides the serial chain): r[BREV(k1)] *= w^k1, w = e^{DIR*2pi*i*t/256}.
template<int DIR>
__device__ __forceinline__ void twiddle_reg(vf2 r[16], int t){
    float sn, cn; __sincosf((float)DIR * 0.0245436926f * (float)t, &sn, &cn);
    vf2 w; w.x = cn; w.y = sn;
    vf2 wk = w;
#pragma unroll
    for (int k1 = 1; k1 < 16; ++k1){
        r[BREV(k1)] = cmul(r[BREV(k1)], wk);
        wk = cmul(wk, w);
    }
}

// Intra-wave transpose core for the t-FAST layout (t = tid&15, l = tid>>4):
// transposes are INTRA-WAVE; lines l and l^2 time-share one LDS line in two
// phases; same-wave DS ops execute in issue order -> no s_barrier, but the
// phases must not be merged/reordered: sched_barrier(0) fences them and
// phase B iterates in reverse.
__device__ __forceinline__ void wave_transpose(vf2 r[16], vf2* shw, int t, int l){
    vf2* base = shw + ((l >> 2)*2 + (l & 1))*LSTR;        // line shared by l and l^2
    if ((l & 2) == 0){                                    // phase A: l_local 0,1
#pragma unroll
        for (int k1 = 0; k1 < 16; ++k1) base[k1*16 + (t ^ k1)] = r[BREV(k1)];
#pragma unroll
        for (int n2 = 0; n2 < 16; ++n2) r[n2] = base[t*16 + (n2 ^ t)];
    }
    __builtin_amdgcn_sched_barrier(0);                    // A-reads issue before B-writes
    if ((l & 2) != 0){                                    // phase B: l_local 2,3 (reverse order)
#pragma unroll
        for (int k1 = 15; k1 >= 0; --k1) base[k1*16 + (t ^ k1)] = r[BREV(k1)];
#pragma unroll
        for (int n2 = 15; n2 >= 0; --n2) r[n2] = base[t*16 + (n2 ^ t)];
    }
}

// Barrier-free mid256 (t-fast) with register twiddles: ZERO __syncthreads.
template<int DIR>
__device__ __forceinline__ void mid256wr(vf2 r[16], vf2* shw, int t, int l){
    fft16<DIR>(r);
    twiddle_reg<DIR>(r, t);
    wave_transpose(r, shw, t, l);
    fft16<DIR>(r);
}

// TWO-COLUMN strided-axis FFT on packed fp16: 32 consecutive x per block
// (2 per thread, uint2 = 128B/16 lanes). Reads idx<NIN (rest zero) scaled by
// insc at load (fold point for range safety); writes idx<NOUT unscaled.
template<int DIR, int NIN, int NOUT>
__device__ __forceinline__ void fft_strided2(unsigned* g, int S, float insc){
    __shared__ unsigned shp[16*LSTR];
    __shared__ vf2 tw[256];
    int t = threadIdx.x >> 4, l = threadIdx.x & 15;
    vf2 r[2][16];
    vf2 zero; zero.x = 0.f; zero.y = 0.f;
#pragma unroll
    for (int n1 = 0; n1 < 16; ++n1){
        if (n1 < NIN/16){
            uint2 ld = *reinterpret_cast<const uint2*>(&g[(size_t)(16*n1 + t)*S + 2*l]);
            r[0][n1] = uph(ld.x)*insc;
            r[1][n1] = uph(ld.y)*insc;
        } else { r[0][n1] = zero; r[1][n1] = zero; }
    }
    init_tw(tw, (float)DIR);
    __syncthreads();                                 // tw ready
    mid256t2<DIR>(r, shp, tw, t, l);
#pragma unroll
    for (int k2 = 0; k2 < 16; ++k2)
        if (k2 < NOUT/16){
            uint2 st; st.x = pkh(r[0][BREV(k2)]); st.y = pkh(r[1][BREV(k2)]);
            *reinterpret_cast<uint2*>(&g[(size_t)(t + 16*k2)*S + 2*l]) = st;
        }
}

// P1: read input, val = sqrt(relu(f*gz^2)), zero-pad 128->256, forward FFT along x
// with the half-pixel x-average folded ALGEBRAICALLY:
//   out[k] = FFT( x[n] * 0.5*(1 + e^{+2pi i n/256}) )[k]   (cyclic part)
//   out[128] = 0.5 * sum_n (-1)^n x[n]                      (dropped tap at k=128)
// t-FAST layout, mid256wr, ZERO __syncthreads. Stores fp16-packed A (scale 1).
__global__ void __launch_bounds__(256) k_p1(const float* __restrict__ in, unsigned* __restrict__ A){
    __shared__ vf2 sh8[8*LSTR];
    int tid = threadIdx.x, bid = blockIdx.x;         // v*1024 + z*8 + yc
    int yc = bid & 7, z = (bid >> 3) & 127, v = bid >> 10;
    int t = tid & 15, l = tid >> 4;                  // lanes 0..15 = consecutive x
    float gz = z * (1.0f/127.0f);
    float g2 = gz*gz;
    const float* src = in + (((size_t)(v*128 + z))*128 + yc*16 + l)*128;  // row y=yc*16+l
    float val[8];
#pragma unroll
    for (int n1 = 0; n1 < 8; ++n1) val[n1] = src[16*n1 + t];   // loads issue first
#pragma unroll
    for (int n1 = 0; n1 < 8; ++n1){
        float x = val[n1] * g2;
        val[n1] = x > 0.f ? sqrtf(x) : 0.f;
    }
    // k=128 fix-up: S = sum_n (-1)^n x[n]; sign = (-1)^t. Intra-row butterfly over t.
    float part = ((val[0]+val[1]) + (val[2]+val[3])) + ((val[4]+val[5]) + (val[6]+val[7]));
    part = (t & 1) ? -part : part;
    part += __shfl_xor(part, 1);
    part += __shfl_xor(part, 2);
    part += __shfl_xor(part, 4);
    part += __shfl_xor(part, 8);
    // prefilter (input real): r[n] = x[n] * 0.5*(1+cos, sin), theta = 2pi n/256
    vf2 r[16];
    vf2 zero; zero.x = 0.f; zero.y = 0.f;
#pragma unroll
    for (int n1 = 8; n1 < 16; ++n1) r[n1] = zero;
#pragma unroll
    for (int n1 = 0; n1 < 8; ++n1){
        float sn, cn; __sincosf(0.0245436926f * (float)(16*n1 + t), &sn, &cn);
        r[n1].x = val[n1] * 0.5f * (1.f + cn);
        r[n1].y = val[n1] * 0.5f * sn;
    }
    mid256wr<-1>(r, sh8, t, l);
    if (t == 0){ r[1].x = part*0.5f; r[1].y = 0.f; } // BREV(8)=1 -> X[128], real
    unsigned* dst = A + (size_t)v*VS + (size_t)z*ZSTR + (size_t)(yc*16 + l)*YSTR;
#pragma unroll
    for (int k2 = 0; k2 < 16; ++k2)                  // x = t+16*k2, 16 lanes = 64B
        dst[t + 16*k2] = pkh(r[BREV(k2)]);
}

// P2z: forward FFT along z (before y-FFT: only y<128 columns exist -> half
// traffic). Read z<128, write z<128. In-place, scale 1 (mid<=2k, fp16-safe).
// 32 x per block (2/thread).
__global__ void __launch_bounds__(256) k_p2z(unsigned* __restrict__ A){
    int bid = blockIdx.x;                            // v*1024 + y*8 + xb   (y < 128)
    int xb = bid & 7, y = (bid >> 3) & 127, v = bid >> 10;
    fft_strided2<-1,128,128>(A + (size_t)v*VS + (size_t)y*YSTR + xb*32, ZSTR, 1.f);
}

// P3y: forward FFT along y for each z<128 slab (read y<128, write 256).
// Half-pixel y-average folded algebraically; 2^-6 scale folded into the
// PREFILTER so the fp16 LDS transpose midpoints stay in range (<=4k).
// 32 x per block (2/thread).
__global__ void __launch_bounds__(256) k_p3y(unsigned* __restrict__ A){
    __shared__ unsigned shp[16*LSTR];
    __shared__ vf2 tw[256];
    __shared__ vf2 shW[128];                         // per-wave partials, 2 cols
    const float SC3 = 0.015625f;                     // 2^-6
    int bid = blockIdx.x;                            // v*1024 + z*8 + xb   (z < 128)
    int xb = bid & 7, z = (bid >> 3) & 127, v = bid >> 10;
    unsigned* g = A + (size_t)v*VS + (size_t)z*ZSTR + xb*32;
    int t = threadIdx.x >> 4, l = threadIdx.x & 15;
    vf2 r[2][16];
    vf2 zero; zero.x = 0.f; zero.y = 0.f;
#pragma unroll
    for (int n1 = 0; n1 < 16; ++n1){
        if (n1 < 8){
            uint2 ld = *reinterpret_cast<const uint2*>(&g[(size_t)(16*n1 + t)*YSTR + 2*l]);
            r[0][n1] = uph(ld.x);
            r[1][n1] = uph(ld.y);
        } else { r[0][n1] = zero; r[1][n1] = zero; }
    }
    // alternating-sum partial from RAW inputs: (-1)^n = (-1)^t since 16*n1 even.
#pragma unroll
    for (int c = 0; c < 2; ++c){
        vf2 part = ((r[c][0]+r[c][1]) + (r[c][2]+r[c][3])) + ((r[c][4]+r[c][5]) + (r[c][6]+r[c][7]));
        part = part * ((t & 1) ? -1.f : 1.f);
        part.x += __shfl_xor(part.x, 16);            // t ^ 1  (within wave)
        part.y += __shfl_xor(part.y, 16);
        part.x += __shfl_xor(part.x, 32);            // t ^ 2  (within wave)
        part.y += __shfl_xor(part.y, 32);
        if ((t & 3) == 0) shW[(t >> 2)*32 + 2*l + c] = part;  // per (wave, col)
    }
    // cyclic-average pre-filter x SC3: r[n] *= SC3*0.5*(1 + e^{+2pi i n/256})
#pragma unroll
    for (int n1 = 0; n1 < 8; ++n1){
        float sn, cn; __sincosf(0.0245436926f * (float)(16*n1 + t), &sn, &cn);
        vf2 c; c.x = SC3*0.5f*(1.f + cn); c.y = SC3*0.5f*sn;
        r[0][n1] = cmul(r[0][n1], c);
        r[1][n1] = cmul(r[1][n1], c);
    }
    init_tw(tw, -1.f);
    __syncthreads();                                 // tw + shW ready
    mid256t2<-1>(r, shp, tw, t, l);
    if (t == 0){                                     // k = 128 fix-up (t=0, k2=8)
#pragma unroll
        for (int c = 0; c < 2; ++c){
            vf2 S = (shW[2*l + c] + shW[32 + 2*l + c]) + (shW[64 + 2*l + c] + shW[96 + 2*l + c]);
            r[c][BREV(8)] = S * (0.5f*SC3);
        }
    }
#pragma unroll
    for (int k2 = 0; k2 < 16; ++k2){                 // uint2 store: 16 lanes = 128B
        uint2 st; st.x = pkh(r[0][BREV(k2)]); st.y = pkh(r[1][BREV(k2)]);
        *reinterpret_cast<uint2*>(&g[(size_t)(t + 16*k2)*YSTR + 2*l]) = st;
    }
}

// P45: fused Stolt z-resample (2 taps) + x-iFFT. Direct global->register gather
// (t=tid&15 lane-fast) and direct register->global store. t-fast + register
// twiddles -> ZERO barriers. Gather-BW-bound (r5).
// r11: XCD-aware CHUNKED block swizzle (T1) -- adjacent-zn blocks gather
// overlapping A z-tap rows; giving each XCD a contiguous zn range turns the
// cross-XCD L3 re-fetches into per-XCD L2 hits. Bijective: 4096 % 8 == 0.
__global__ void __launch_bounds__(256) k_p45(const unsigned* __restrict__ A, unsigned* __restrict__ B){
    __shared__ vf2 sh8[8*LSTR];
    int tid = threadIdx.x;
    int bid0 = blockIdx.x;                           // HW round-robins bid0%8 across XCDs
    int bid = (bid0 & 7)*512 + (bid0 >> 3);          // XCD k owns contiguous [k*512,(k+1)*512)
    int yc = bid & 15, zn = (bid >> 4) & 127, v = bid >> 11;
    const unsigned* Av = A + (size_t)v*VS;
    int t = tid & 15, l = tid >> 4;                  // lanes 0..15 = consecutive x
    int yn = yc*16 + l;
    float gy = (yn < 128 ? yn : yn - 256) * (1.0f/128.0f);
    float gz = zn * (1.0f/128.0f);
    float c2 = 0.1024f*gy*gy + gz*gz;
    unsigned rowoff = (unsigned)yn*YSTR;
    vf2 r[16];
#pragma unroll
    for (int n1 = 0; n1 < 16; ++n1){
        int xn = 16*n1 + t;
        float gx = (xn < 128 ? xn : xn - 256) * (1.0f/128.0f);
        float s2 = c2 + 0.1024f*gx*gx;
        float rs = __builtin_amdgcn_rsqf(s2 + 1e-12f);   // 1/gznew; zn==0 row -> wf=0
        float gznew = s2 * rs;
        float pz = gznew*128.0f + 127.5f;
        int zi = (int)pz;                                // trunc == floor (pz>0)
        float dz = pz - (float)zi;
        int zp0 = zi - 128;                              // natural z of first tap
        float wf = gz * rs;                              // gz/gznew
        float w0 = (((unsigned)zp0     < 128u) ? (1.0f - dz) : 0.f) * wf;
        float w1 = (((unsigned)(zp0+1) < 128u) ? dz : 0.f) * wf;
        vf2 v0 = uph(Av[(size_t)((unsigned)(zp0 & 127) * ZSTR) + rowoff + xn]);
        vf2 v1 = uph(Av[(size_t)((unsigned)((zp0 + 1) & 127) * ZSTR) + rowoff + xn]);
        r[n1] = v0*w0 + v1*w1;
    }
    mid256wr<1>(r, sh8, t, l);
    unsigned* dst = B + (size_t)v*VSB + (size_t)zn*BZS + (size_t)yn*BYS;
#pragma unroll
    for (int k2 = 0; k2 < 8; ++k2)                   // x = t+16*k2 < 128, coalesced
        dst[t + 16*k2] = pkh(r[BREV(k2)]);
}

// P6: inverse FFT along y on packed B (x<128). Read 256 y, write y<128.
// 2^-8 scale folded at LOAD (fp16 LDS mid <=4k). 32 x per block (2/thread).
__global__ void __launch_bounds__(256) k_p6(unsigned* __restrict__ B){
    int bid = blockIdx.x;                            // v*512 + zn*4 + xb
    int xb = bid & 3, zn = (bid >> 2) & 127, v = bid >> 9;
    fft_strided2<1,256,128>(B + (size_t)v*VSB + (size_t)zn*BZS + xb*32, BYS, 0.00390625f);
}

// P7: inverse FFT along z for y<128, x<128 on packed B. Read zn<128 scaled by
// residual 2^-10 at load (total = 2^-24 = 1/256^3), write fp32 real out as
// float2 (2 adjacent x). 32 x per block (2/thread).
__global__ void __launch_bounds__(256) k_p7(const unsigned* __restrict__ B, float* __restrict__ out){
    __shared__ unsigned shp[16*LSTR];
    __shared__ vf2 tw[256];
    const float sc = 9.765625e-4f;                   // 2^-10
    int bid = blockIdx.x;                            // v*512 + y*4 + xb
    int xb = bid & 3, y = (bid >> 2) & 127, v = bid >> 9;
    const unsigned* g = B + (size_t)v*VSB + (size_t)y*BYS + xb*32;
    int t = threadIdx.x >> 4, l = threadIdx.x & 15;
    vf2 r[2][16];
    vf2 zero; zero.x = 0.f; zero.y = 0.f;
#pragma unroll
    for (int n1 = 0; n1 < 16; ++n1){
        if (n1 < 8){
            uint2 ld = *reinterpret_cast<const uint2*>(&g[(size_t)(16*n1 + t)*BZS + 2*l]);
            r[0][n1] = uph(ld.x)*sc;
            r[1][n1] = uph(ld.y)*sc;
        } else { r[0][n1] = zero; r[1][n1] = zero; }
    }
    init_tw(tw, 1.f);
    __syncthreads();
    mid256t2<1>(r, shp, tw, t, l);
    float* dst = out + ((size_t)(v*128)*128 + y)*128 + xb*32 + 2*l;
#pragma unroll
    for (int k2 = 0; k2 < 8; ++k2){                  // k = t + 16*k2 < 128
        float2 st; st.x = r[0][BREV(k2)].x; st.y = r[1][BREV(k2)].x;
        *reinterpret_cast<float2*>(&dst[(size_t)(t + 16*k2)*16384]) = st;
    }
}

extern "C" void kernel_launch(void* const* d_in, const int* in_sizes, int n_in,
                              void* d_out, int out_size, void* d_ws, size_t ws_size,
                              hipStream_t stream){
    const float* in = (const float*)d_in[0];
    float* out = (float*)d_out;
    unsigned* A = (unsigned*)d_ws;         // 67 MB (fp16-packed)
    unsigned* B = A + 2*VS;                // 33.5 MB (fp16-packed)
    k_p1 <<< 2048, 256, 0, stream>>>(in, A);
    k_p2z<<< 2048, 256, 0, stream>>>(A);   // z-FFT first: y<128 -> half traffic
    k_p3y<<< 2048, 256, 0, stream>>>(A);
    k_p45<<< 4096, 256, 0, stream>>>(A, B);
    k_p6 <<< 1024, 256, 0, stream>>>(B);
    k_p7 <<< 1024, 256, 0, stream>>>(B, out);
}